// Round 6
// baseline (220.068 us; speedup 1.0000x reference)
//
#include <hip/hip_runtime.h>
#include <hip/hip_bf16.h>

#define BB 4
#define NN 200
#define HH 300
#define KSN 10            // k-steps of 32 (K padded to 320)
#define GHF 10            // g-frags of 16 per g-half (G padded to 320)
#define NTILES 5000       // 160,000 rows / 32 rows per wave-tile
#define BHALF_BYTES (KSN * GHF * 1024)   // 102,400 B of frag-packed B per g-half

typedef __attribute__((ext_vector_type(8))) short short8;
typedef __attribute__((ext_vector_type(4))) float float4v;

static __device__ __forceinline__ ushort f2bf(float x) {
    union { float f; uint u; } v; v.f = x;
    uint r = v.u + 0x7FFFu + ((v.u >> 16) & 1u);  // RNE
    return (ushort)(r >> 16);
}

static __device__ __forceinline__ short8 pack8(float4v a, float4v b) {
    short8 r;
    r[0] = (short)f2bf(a[0]); r[1] = (short)f2bf(a[1]);
    r[2] = (short)f2bf(a[2]); r[3] = (short)f2bf(a[3]);
    r[4] = (short)f2bf(b[0]); r[5] = (short)f2bf(b[1]);
    r[6] = (short)f2bf(b[2]); r[7] = (short)f2bf(b[3]);
    return r;
}

static __device__ __forceinline__ void gload_lds16(const void* g, void* l) {
    __builtin_amdgcn_global_load_lds(
        (const __attribute__((address_space(1))) unsigned int*)g,
        (__attribute__((address_space(3))) unsigned int*)l, 16, 0, 0);
}

static __device__ __forceinline__ int wave_grab(int* c, int lane) {
    int t = 0;
    if (lane == 0) t = atomicAdd(c, 1);
    return __shfl(t, 0);
}

// Pack U_w (g,h) f32 -> bf16 frag order, g-half-major:
// idx = ((gh*KSN + ks)*GHF + fh)*64 + lane ; elem j: g=(gh*GHF+fh)*16+(lane&15), h=ks*32+(lane>>4)*8+j
__global__ void pack_u(const float* __restrict__ Uw, ushort* __restrict__ Bp, int* __restrict__ cnt) {
    int idx = blockIdx.x * 256 + threadIdx.x;
    if (idx == 0) { cnt[0] = 0; cnt[1] = 0; }
    if (idx >= 2 * KSN * GHF * 64) return;
    int lane = idx & 63;
    int rem = idx >> 6;                 // 0..199
    int fh = rem % GHF;
    int ks = (rem / GHF) % KSN;
    int gh = rem / (GHF * KSN);
    int g = (gh * GHF + fh) * 16 + (lane & 15);
    int h0 = ks * 32 + (lane >> 4) * 8;
    ushort v[8];
#pragma unroll
    for (int j = 0; j < 8; ++j) {
        int h = h0 + j;
        v[j] = (g < HH && h < HH) ? f2bf(Uw[g * HH + h]) : (ushort)0;
    }
    *reinterpret_cast<short8*>(Bp + (size_t)idx * 8) = *reinterpret_cast<const short8*>(v);
}

// Vx[b,n,g] = sum_h x[b,n,h]*Vw[g,h] + Vb[g] + 0.5*Ub[g]   (Ub folded: vi'+vj' = vi+vj+Ub)
__global__ void vx_kernel(const float* __restrict__ x, const float* __restrict__ Vw,
                          const float* __restrict__ Vb, const float* __restrict__ Ub,
                          float* __restrict__ Vx) {
    __shared__ float xs[HH];
    int row = blockIdx.x;
    const float* xr = x + (size_t)row * HH;
    for (int h = threadIdx.x; h < HH; h += 256) xs[h] = xr[h];
    __syncthreads();
    for (int g = threadIdx.x; g < HH; g += 256) {
        const float4* wr = reinterpret_cast<const float4*>(Vw + (size_t)g * HH);
        const float4* xv = reinterpret_cast<const float4*>(xs);
        float s0 = 0.f, s1 = 0.f, s2 = 0.f, s3 = 0.f;
#pragma unroll 5
        for (int k = 0; k < HH / 4; ++k) {
            float4 w = wr[k];
            float4 xx = xv[k];
            s0 += w.x * xx.x; s1 += w.y * xx.y; s2 += w.z * xx.z; s3 += w.w * xx.w;
        }
        Vx[(size_t)row * HH + g] = Vb[g] + 0.5f * Ub[g] + s0 + s1 + s2 + s3;
    }
}

// Persistent blocks: 256 blocks x 512 threads (8 waves), 1 block/CU (100 KB LDS).
// Block stages its g-half of B into LDS ONCE, then waves free-run (no barriers):
// each wave pulls 32-row tiles from an atomic queue; per tile: 10 ks x
// (2 A-frags from global, 10 B ds_reads shared by both, 20 MFMA). A prefetched
// 2 k-steps ahead in a 2-set rotating register file, rolling into next tile.
__launch_bounds__(512, 2)
__global__ void gemm_kernel(const float* __restrict__ e, const ushort* __restrict__ Bp,
                            const float* __restrict__ Vx, float* __restrict__ out,
                            int* __restrict__ cnt) {
    __shared__ ushort Blds[BHALF_BYTES / 2];   // 51,200 ushorts = 100 KB
    const int tid = threadIdx.x;
    const int lane = tid & 63;
    const int gh = blockIdx.x & 1;
    const int r = lane & 15, q = lane >> 4;

    // ---- stage B g-half into LDS (once) ----
    const char* bsrc = (const char*)Bp + (size_t)gh * BHALF_BYTES;
#pragma unroll
    for (int i = 0; i < 13; ++i) {
        int off = tid * 16 + i * 8192;
        if (off < BHALF_BYTES)   // wave-uniform (boundary at tid==256)
            gload_lds16(bsrc + off, (char*)Blds + off);
    }

    int* mycnt = cnt + gh;
    int T = wave_grab(mycnt, lane);
    int Ts = T < NTILES ? T : 0;
    const float* rowA = e + (size_t)(Ts * 32 + r) * HH;
    const float* rowB = rowA + 16 * HH;

    // rotating A-register sets: set0 = even ks, set1 = odd ks
    float4v a00, a01, b00, b01, a10, a11, b10, b11;
    const int kq = q * 8;
    a00 = *reinterpret_cast<const float4v*>(rowA + kq);
    a01 = *reinterpret_cast<const float4v*>(rowA + kq + 4);
    b00 = *reinterpret_cast<const float4v*>(rowB + kq);
    b01 = *reinterpret_cast<const float4v*>(rowB + kq + 4);
    a10 = *reinterpret_cast<const float4v*>(rowA + 32 + kq);
    a11 = *reinterpret_cast<const float4v*>(rowA + 32 + kq + 4);
    b10 = *reinterpret_cast<const float4v*>(rowB + 32 + kq);
    b11 = *reinterpret_cast<const float4v*>(rowB + 32 + kq + 4);

    asm volatile("s_waitcnt vmcnt(0)" ::: "memory");
    __syncthreads();   // one-time: LDS B ready for all waves

    while (T < NTILES) {
        int Tn = wave_grab(mycnt, lane);           // next tile id (latency hidden by tile)
        int Tns = Tn < NTILES ? Tn : 0;
        const float* rowAn = e + (size_t)(Tns * 32 + r) * HH;
        const float* rowBn = rowAn + 16 * HH;

        float4v acc0[GHF], acc1[GHF];
#pragma unroll
        for (int f = 0; f < GHF; ++f) {
            acc0[f] = (float4v){0.f, 0.f, 0.f, 0.f};
            acc1[f] = (float4v){0.f, 0.f, 0.f, 0.f};
        }

        // consume set, prefetch ks+2 into same set (rolls into next tile at ks2>=10)
#define BODY(KS_, A0_, A1_, B0_, B1_) do {                                        \
        short8 fa_ = pack8(A0_, A1_);                                             \
        short8 fb_ = pack8(B0_, B1_);                                             \
        {                                                                         \
            int ks2_ = (KS_) + 2;                                                 \
            bool nxt_ = ks2_ >= KSN;                                              \
            const float* ra_ = nxt_ ? rowAn : rowA;                               \
            const float* rb_ = nxt_ ? rowBn : rowB;                               \
            int c0_ = (nxt_ ? ks2_ - KSN : ks2_) * 32 + kq;                       \
            const float* p0_ = (c0_ + 4 <= HH) ? ra_ + c0_ : e;                   \
            const float* p1_ = (c0_ + 8 <= HH) ? ra_ + c0_ + 4 : e;               \
            const float* p2_ = (c0_ + 4 <= HH) ? rb_ + c0_ : e;                   \
            const float* p3_ = (c0_ + 8 <= HH) ? rb_ + c0_ + 4 : e;               \
            A0_ = *reinterpret_cast<const float4v*>(p0_);                         \
            A1_ = *reinterpret_cast<const float4v*>(p1_);                         \
            B0_ = *reinterpret_cast<const float4v*>(p2_);                         \
            B1_ = *reinterpret_cast<const float4v*>(p3_);                         \
        }                                                                         \
        const ushort* bb_ = Blds + (KS_) * (GHF * 512) + lane * 8;                \
        _Pragma("unroll")                                                         \
        for (int f_ = 0; f_ < GHF; ++f_) {                                        \
            short8 bf_ = *reinterpret_cast<const short8*>(bb_ + f_ * 512);        \
            acc0[f_] = __builtin_amdgcn_mfma_f32_16x16x32_bf16(fa_, bf_, acc0[f_], 0, 0, 0); \
            acc1[f_] = __builtin_amdgcn_mfma_f32_16x16x32_bf16(fb_, bf_, acc1[f_], 0, 0, 0); \
        }                                                                         \
    } while (0)

#pragma unroll 1
        for (int u = 0; u < 5; ++u) {
            const int ks0 = 2 * u;
            BODY(ks0,     a00, a01, b00, b01);
            BODY(ks0 + 1, a10, a11, b10, b11);
        }
#undef BODY

        // ---- epilogue: out[m][g] = acc + Vx'[i][g] + Vx'[j][g] ----
        const int gb = gh * (GHF * 16);
#pragma unroll
        for (int t2 = 0; t2 < 2; ++t2) {
#pragma unroll
            for (int r4 = 0; r4 < 4; ++r4) {
                int m = T * 32 + t2 * 16 + q * 4 + r4;
                int j = m % NN;
                int ti = m / NN;        // b*NN + i
                int b = ti / NN;
                const float* vi = Vx + (size_t)ti * HH;
                const float* vj = Vx + (size_t)(b * NN + j) * HH;
                float* orow = out + (size_t)m * HH;
#pragma unroll
                for (int f = 0; f < GHF; ++f) {
                    int g = gb + f * 16 + r;
                    if (g < HH) {
                        float v = (t2 ? acc1[f][r4] : acc0[f][r4]) + vi[g] + vj[g];
                        orow[g] = v;
                    }
                }
            }
        }

        T = Tn;
        rowA = rowAn;
        rowB = rowBn;
    }
}

extern "C" void kernel_launch(void* const* d_in, const int* in_sizes, int n_in,
                              void* d_out, int out_size, void* d_ws, size_t ws_size,
                              hipStream_t stream) {
    const float* x  = (const float*)d_in[0];
    const float* e  = (const float*)d_in[1];
    const float* Uw = (const float*)d_in[2];
    const float* Ub = (const float*)d_in[3];
    const float* Vw = (const float*)d_in[4];
    const float* Vb = (const float*)d_in[5];
    float* out = (float*)d_out;

    ushort* Bp = (ushort*)d_ws;                              // 204,800 B
    float*  Vx = (float*)((char*)d_ws + 204800);             // 960,000 B
    int*    cnt = (int*)((char*)d_ws + 204800 + 960000);     // 8 B (zeroed by pack_u)

    pack_u<<<50, 256, 0, stream>>>(Uw, Bp, cnt);
    vx_kernel<<<BB * NN, 256, 0, stream>>>(x, Vw, Vb, Ub, Vx);
    gemm_kernel<<<256, 512, 0, stream>>>(e, Bp, Vx, out, cnt);
}

// Round 7
// 179.753 us; speedup vs baseline: 1.2243x; 1.2243x over previous
//
#include <hip/hip_runtime.h>
#include <hip/hip_bf16.h>

#define BB 4
#define NN 200
#define HH 300
#define KSN 10            // k-steps of 32 (K padded to 320)
#define GHF 10            // g-frags of 16 per g-half (G padded to 320)
#define NTH 5000          // 32-row tiles per g-half (160000/32)
#define SLOTS 1024        // wave slots per g-half (128 blocks x 8 waves)
#define BHALF_BYTES (KSN * GHF * 1024)   // 102,400 B frag-packed B per g-half

typedef __attribute__((ext_vector_type(8))) short short8;
typedef __attribute__((ext_vector_type(4))) float float4v;

static __device__ __forceinline__ ushort f2bf(float x) {
    union { float f; uint u; } v; v.f = x;
    uint r = v.u + 0x7FFFu + ((v.u >> 16) & 1u);  // RNE
    return (ushort)(r >> 16);
}

// 2 f32 -> packed 2x bf16 (RNE) in one instr; 4 per 8-elem fragment
static __device__ __forceinline__ short8 pack8_cvt(float4v a, float4v b) {
    uint u0, u1, u2, u3;
    asm("v_cvt_pk_bf16_f32 %0, %1, %2" : "=v"(u0) : "v"(a[0]), "v"(a[1]));
    asm("v_cvt_pk_bf16_f32 %0, %1, %2" : "=v"(u1) : "v"(a[2]), "v"(a[3]));
    asm("v_cvt_pk_bf16_f32 %0, %1, %2" : "=v"(u2) : "v"(b[0]), "v"(b[1]));
    asm("v_cvt_pk_bf16_f32 %0, %1, %2" : "=v"(u3) : "v"(b[2]), "v"(b[3]));
    union { uint u[4]; short8 s; } r;
    r.u[0] = u0; r.u[1] = u1; r.u[2] = u2; r.u[3] = u3;
    return r.s;
}

static __device__ __forceinline__ void gload_lds16(const void* g, void* l) {
    __builtin_amdgcn_global_load_lds(
        (const __attribute__((address_space(1))) unsigned int*)g,
        (__attribute__((address_space(3))) unsigned int*)l, 16, 0, 0);
}

// Pack U_w (g,h) f32 -> bf16 frag order, g-half-major:
// idx = ((gh*KSN + ks)*GHF + fh)*64 + lane ; elem j: g=(gh*GHF+fh)*16+(lane&15), h=ks*32+(lane>>4)*8+j
__global__ void pack_u(const float* __restrict__ Uw, ushort* __restrict__ Bp) {
    int idx = blockIdx.x * 256 + threadIdx.x;
    if (idx >= 2 * KSN * GHF * 64) return;
    int lane = idx & 63;
    int rem = idx >> 6;
    int fh = rem % GHF;
    int ks = (rem / GHF) % KSN;
    int gh = rem / (GHF * KSN);
    int g = (gh * GHF + fh) * 16 + (lane & 15);
    int h0 = ks * 32 + (lane >> 4) * 8;
    ushort v[8];
#pragma unroll
    for (int j = 0; j < 8; ++j) {
        int h = h0 + j;
        v[j] = (g < HH && h < HH) ? f2bf(Uw[g * HH + h]) : (ushort)0;
    }
    *reinterpret_cast<short8*>(Bp + (size_t)idx * 8) = *reinterpret_cast<const short8*>(v);
}

// Vx[b,n,g] = sum_h x[b,n,h]*Vw[g,h] + Vb[g] + 0.5*Ub[g]  (Ub folded: vi'+vj' = vi+vj+Ub)
__global__ void vx_kernel(const float* __restrict__ x, const float* __restrict__ Vw,
                          const float* __restrict__ Vb, const float* __restrict__ Ub,
                          float* __restrict__ Vx) {
    __shared__ float xs[HH];
    int row = blockIdx.x;
    const float* xr = x + (size_t)row * HH;
    for (int h = threadIdx.x; h < HH; h += 256) xs[h] = xr[h];
    __syncthreads();
    for (int g = threadIdx.x; g < HH; g += 256) {
        const float4* wr = reinterpret_cast<const float4*>(Vw + (size_t)g * HH);
        const float4* xv = reinterpret_cast<const float4*>(xs);
        float s0 = 0.f, s1 = 0.f, s2 = 0.f, s3 = 0.f;
#pragma unroll 5
        for (int k = 0; k < HH / 4; ++k) {
            float4 w = wr[k];
            float4 xx = xv[k];
            s0 += w.x * xx.x; s1 += w.y * xx.y; s2 += w.z * xx.z; s3 += w.w * xx.w;
        }
        Vx[(size_t)row * HH + g] = Vb[g] + 0.5f * Ub[g] + s0 + s1 + s2 + s3;
    }
}

// Persistent: 256 blocks x 512 thr (8 waves), 1 block/CU (100 KB LDS for B g-half).
// Static schedule: wave slot s handles tiles s, s+1024, ... (no atomics, no barriers
// after the one-time B stage). Swapped MFMA operands: acc reg-index = g (4 consecutive),
// lane&15 = m -> float4 epilogue stores. A prefetched 5 k-steps ahead in a 5-set
// rotating register file that rolls into the next tile's rows.
__launch_bounds__(512, 2)
__global__ void gemm_kernel(const float* __restrict__ e, const ushort* __restrict__ Bp,
                            const float* __restrict__ Vx, float* __restrict__ out) {
    __shared__ ushort Blds[BHALF_BYTES / 2];   // 100 KB
    const int tid = threadIdx.x;
    const int lane = tid & 63, wave = tid >> 6;
    const int gh = blockIdx.x >> 7;           // 0..1 (blocks 0-127: gh0, 128-255: gh1)
    const int bslot = blockIdx.x & 127;
    const int slot = bslot * 8 + wave;        // 0..1023 within g-half
    const int r = lane & 15, q = lane >> 4;
    const int kq = q * 8;

    // ---- one-time B g-half stage into LDS ----
    const char* bsrc = (const char*)Bp + (size_t)gh * BHALF_BYTES;
#pragma unroll
    for (int i = 0; i < 13; ++i) {
        int off = i * 8192 + tid * 16;
        if (off < BHALF_BYTES)   // wave-uniform boundary (tid<256 at i=12)
            gload_lds16(bsrc + off, (char*)Blds + off);
    }

    int T = slot;
    const float* rowA = e + (size_t)(T * 32 + r) * HH;
    const float* rowB = rowA + 16 * HH;

    // load one A-set (4x float4): rows r / r+16, cols KS*32+kq .. +8, tail-clamped
#define LOADSET(PA0, PA1, PB0, PB1, RA_, RB_, KS_) do {                        \
        int c0_ = (KS_) * 32 + kq;                                             \
        const float* p0_ = (c0_ + 4 <= HH) ? (RA_) + c0_ : e;                  \
        const float* p1_ = (c0_ + 8 <= HH) ? (RA_) + c0_ + 4 : e;              \
        const float* p2_ = (c0_ + 4 <= HH) ? (RB_) + c0_ : e;                  \
        const float* p3_ = (c0_ + 8 <= HH) ? (RB_) + c0_ + 4 : e;              \
        PA0 = *reinterpret_cast<const float4v*>(p0_);                          \
        PA1 = *reinterpret_cast<const float4v*>(p1_);                          \
        PB0 = *reinterpret_cast<const float4v*>(p2_);                          \
        PB1 = *reinterpret_cast<const float4v*>(p3_);                          \
    } while (0)

    // 5 rotating A-sets (named -> static reg allocation)
    float4v s0a0, s0a1, s0b0, s0b1, s1a0, s1a1, s1b0, s1b1,
            s2a0, s2a1, s2b0, s2b1, s3a0, s3a1, s3b0, s3b1,
            s4a0, s4a1, s4b0, s4b1;

    LOADSET(s0a0, s0a1, s0b0, s0b1, rowA, rowB, 0);
    LOADSET(s1a0, s1a1, s1b0, s1b1, rowA, rowB, 1);
    LOADSET(s2a0, s2a1, s2b0, s2b1, rowA, rowB, 2);
    LOADSET(s3a0, s3a1, s3b0, s3b1, rowA, rowB, 3);
    LOADSET(s4a0, s4a1, s4b0, s4b1, rowA, rowB, 4);

    asm volatile("s_waitcnt vmcnt(0)" ::: "memory");
    __syncthreads();   // one-time: B LDS ready; no barriers after this

#define BODY(KS_, SA0, SA1, SB0, SB1, RA_, RB_, PKS_) do {                     \
        short8 fa_ = pack8_cvt(SA0, SA1);                                      \
        short8 fb_ = pack8_cvt(SB0, SB1);                                      \
        LOADSET(SA0, SA1, SB0, SB1, RA_, RB_, PKS_);                           \
        const ushort* bb_ = Blds + (KS_) * (GHF * 512) + lane * 8;             \
        _Pragma("unroll")                                                      \
        for (int f_ = 0; f_ < GHF; ++f_) {                                     \
            short8 bf_ = *reinterpret_cast<const short8*>(bb_ + f_ * 512);     \
            acc0[f_] = __builtin_amdgcn_mfma_f32_16x16x32_bf16(bf_, fa_, acc0[f_], 0, 0, 0); \
            acc1[f_] = __builtin_amdgcn_mfma_f32_16x16x32_bf16(bf_, fb_, acc1[f_], 0, 0, 0); \
        }                                                                      \
    } while (0)

#pragma unroll 1
    for (int it = 0; it < 5; ++it) {
        if (T >= NTH) break;
        int Tn = T + SLOTS;
        int Tc = (Tn < NTH) ? Tn : 0;          // dummy rows for last tile's roll-prefetch
        const float* rowAn = e + (size_t)(Tc * 32 + r) * HH;
        const float* rowBn = rowAn + 16 * HH;

        float4v acc0[GHF], acc1[GHF];
#pragma unroll
        for (int f = 0; f < GHF; ++f) {
            acc0[f] = (float4v){0.f, 0.f, 0.f, 0.f};
            acc1[f] = (float4v){0.f, 0.f, 0.f, 0.f};
        }

        BODY(0, s0a0, s0a1, s0b0, s0b1, rowA,  rowB,  5);
        BODY(1, s1a0, s1a1, s1b0, s1b1, rowA,  rowB,  6);
        BODY(2, s2a0, s2a1, s2b0, s2b1, rowA,  rowB,  7);
        BODY(3, s3a0, s3a1, s3b0, s3b1, rowA,  rowB,  8);
        BODY(4, s4a0, s4a1, s4b0, s4b1, rowA,  rowB,  9);
        BODY(5, s0a0, s0a1, s0b0, s0b1, rowAn, rowBn, 0);
        BODY(6, s1a0, s1a1, s1b0, s1b1, rowAn, rowBn, 1);
        BODY(7, s2a0, s2a1, s2b0, s2b1, rowAn, rowBn, 2);
        BODY(8, s3a0, s3a1, s3b0, s3b1, rowAn, rowBn, 3);
        BODY(9, s4a0, s4a1, s4b0, s4b1, rowAn, rowBn, 4);

        // ---- epilogue: float4 stores, g = gb + f*16 + q*4 + r4, m = T*32 + t2*16 + r
        const int gb = gh * (GHF * 16);
#pragma unroll
        for (int t2 = 0; t2 < 2; ++t2) {
            int m = T * 32 + t2 * 16 + r;
            int j = m % NN;
            int ti = m / NN;        // b*NN + i
            int b = ti / NN;
            const float* vi = Vx + (size_t)ti * HH;
            const float* vj = Vx + (size_t)(b * NN + j) * HH;
            float* orow = out + (size_t)m * HH;
#pragma unroll
            for (int f = 0; f < GHF; ++f) {
                int g0 = gb + f * 16 + q * 4;
                if (g0 + 4 <= HH) {   // quads never straddle 300 (300 % 4 == 0)
                    float4v v = t2 ? acc1[f] : acc0[f];
                    float4v vi4 = *reinterpret_cast<const float4v*>(vi + g0);
                    float4v vj4 = *reinterpret_cast<const float4v*>(vj + g0);
                    *reinterpret_cast<float4v*>(orow + g0) = v + vi4 + vj4;
                }
            }
        }

        T = Tn;
        rowA = rowAn;
        rowB = rowBn;
    }
#undef BODY
#undef LOADSET
}

extern "C" void kernel_launch(void* const* d_in, const int* in_sizes, int n_in,
                              void* d_out, int out_size, void* d_ws, size_t ws_size,
                              hipStream_t stream) {
    const float* x  = (const float*)d_in[0];
    const float* e  = (const float*)d_in[1];
    const float* Uw = (const float*)d_in[2];
    const float* Ub = (const float*)d_in[3];
    const float* Vw = (const float*)d_in[4];
    const float* Vb = (const float*)d_in[5];
    float* out = (float*)d_out;

    ushort* Bp = (ushort*)d_ws;                              // 204,800 B
    float*  Vx = (float*)((char*)d_ws + 204800);             // 960,000 B

    pack_u<<<50, 256, 0, stream>>>(Uw, Bp);
    vx_kernel<<<BB * NN, 256, 0, stream>>>(x, Vw, Vb, Ub, Vx);
    gemm_kernel<<<256, 512, 0, stream>>>(e, Bp, Vx, out);
}

// Round 8
// 152.951 us; speedup vs baseline: 1.4388x; 1.1752x over previous
//
#include <hip/hip_runtime.h>
#include <hip/hip_bf16.h>

#define BB 4
#define NN 200
#define HH 300
#define KSN 10            // k-steps of 32 (K padded to 320)
#define GF 20             // g-frags of 16 (G padded to 320; frag 19 zero)
#define BM 128            // rows per block
#define NCHUNK 5          // K chunks of 64
#define BCHUNK 40960      // B bytes per chunk (2 ks * 20 frags * 1024)

typedef __attribute__((ext_vector_type(8))) short short8;
typedef __attribute__((ext_vector_type(4))) float float4v;

static __device__ __forceinline__ ushort f2bf(float x) {
    union { float f; uint u; } v; v.f = x;
    uint r = v.u + 0x7FFFu + ((v.u >> 16) & 1u);  // RNE
    return (ushort)(r >> 16);
}

// 8 f32 -> 8 bf16 (RNE) via v_cvt_pk_bf16_f32
static __device__ __forceinline__ short8 pack8_cvt(float4v a, float4v b) {
    uint u0, u1, u2, u3;
    asm("v_cvt_pk_bf16_f32 %0, %1, %2" : "=v"(u0) : "v"(a[0]), "v"(a[1]));
    asm("v_cvt_pk_bf16_f32 %0, %1, %2" : "=v"(u1) : "v"(a[2]), "v"(a[3]));
    asm("v_cvt_pk_bf16_f32 %0, %1, %2" : "=v"(u2) : "v"(b[0]), "v"(b[1]));
    asm("v_cvt_pk_bf16_f32 %0, %1, %2" : "=v"(u3) : "v"(b[2]), "v"(b[3]));
    union { uint u[4]; short8 s; } r;
    r.u[0] = u0; r.u[1] = u1; r.u[2] = u2; r.u[3] = u3;
    return r.s;
}

static __device__ __forceinline__ void gload_lds16(const void* g, void* l) {
    __builtin_amdgcn_global_load_lds(
        (const __attribute__((address_space(1))) unsigned int*)g,
        (__attribute__((address_space(3))) unsigned int*)l, 16, 0, 0);
}

// Pack U_w (g,h) f32 -> bf16 in MFMA frag order:
// Bp[((ks*GF+gf)*64 + lane)*8 + j] = Uw[g=gf*16+(lane&15)][h=ks*32+(lane>>4)*8+j], 0 if OOB
__global__ void pack_u(const float* __restrict__ Uw, ushort* __restrict__ Bp) {
    int idx = blockIdx.x * 256 + threadIdx.x;
    if (idx >= KSN * GF * 64) return;
    int lane = idx & 63;
    int kg = idx >> 6;
    int gf = kg % GF, ks = kg / GF;
    int g = gf * 16 + (lane & 15);
    int h0 = ks * 32 + (lane >> 4) * 8;
    ushort v[8];
#pragma unroll
    for (int j = 0; j < 8; ++j) {
        int h = h0 + j;
        v[j] = (g < HH && h < HH) ? f2bf(Uw[g * HH + h]) : (ushort)0;
    }
    *reinterpret_cast<short8*>(Bp + (size_t)idx * 8) = *reinterpret_cast<const short8*>(v);
}

// Vx[b,n,g] = sum_h x[b,n,h]*Vw[g,h] + Vb[g] + 0.5*Ub[g]   (Ub folded)
__global__ void vx_kernel(const float* __restrict__ x, const float* __restrict__ Vw,
                          const float* __restrict__ Vb, const float* __restrict__ Ub,
                          float* __restrict__ Vx) {
    __shared__ float xs[HH];
    int row = blockIdx.x;
    const float* xr = x + (size_t)row * HH;
    for (int h = threadIdx.x; h < HH; h += 256) xs[h] = xr[h];
    __syncthreads();
    for (int g = threadIdx.x; g < HH; g += 256) {
        const float4* wr = reinterpret_cast<const float4*>(Vw + (size_t)g * HH);
        const float4* xv = reinterpret_cast<const float4*>(xs);
        float s0 = 0.f, s1 = 0.f, s2 = 0.f, s3 = 0.f;
#pragma unroll 5
        for (int k = 0; k < HH / 4; ++k) {
            float4 w = wr[k];
            float4 xx = xv[k];
            s0 += w.x * xx.x; s1 += w.y * xx.y; s2 += w.z * xx.z; s3 += w.w * xx.w;
        }
        Vx[(size_t)row * HH + g] = Vb[g] + 0.5f * Ub[g] + s0 + s1 + s2 + s3;
    }
}

// BM=128 rows x full G per block, 512 thr (8 waves x 16 rows). K in 5 chunks of 64.
// A staged f32 via global_load_lds, double-buffered, 16B-unit XOR-swizzled
// (phys_unit = log_unit ^ (row&15), applied on BOTH global src and ds_read).
// B frag-chunks gload_lds staged, double-buffered. Counted vmcnt, raw barriers.
__launch_bounds__(512, 2)
__global__ void gemm_kernel(const float* __restrict__ e, const ushort* __restrict__ Bp,
                            const float* __restrict__ Vx, float* __restrict__ out) {
    __shared__ float  Af[2][BM][64];          // 2 x 32 KB
    __shared__ ushort Bf[2][BCHUNK / 2];      // 2 x 40 KB
    const int tid = threadIdx.x;
    const int w = tid >> 6, l = tid & 63;
    const int r = l & 15, q = l >> 4;
    const int m0 = blockIdx.x * BM;

#define WAITV(N_) asm volatile("s_waitcnt vmcnt(" #N_ ")" ::: "memory")
#define BAR() do {                                                   \
        __builtin_amdgcn_sched_barrier(0);                           \
        asm volatile("s_waitcnt lgkmcnt(0)" ::: "memory");           \
        __builtin_amdgcn_sched_barrier(0);                           \
        __builtin_amdgcn_s_barrier();                                \
        __builtin_amdgcn_sched_barrier(0);                           \
    } while (0)

    // A chunk stage: 4 rounds, each wave writes 1KB linear LDS (4 rows x 256B).
    // Global src permuted by the unit-swizzle; k-tail (chunk 4, cols>=300) clamped.
#define STAGE_A(KC_, P_) do {                                                   \
        _Pragma("unroll")                                                       \
        for (int rd_ = 0; rd_ < 4; ++rd_) {                                     \
            int row_ = rd_ * 32 + w * 4 + (l >> 4);                             \
            int ucl_ = (l & 15) ^ (row_ & 15);                                  \
            const char* src_ = (const char*)(e + (size_t)(m0 + row_) * HH)      \
                               + (KC_) * 256 + ucl_ * 16;                       \
            if ((KC_) == 4 && ucl_ >= 11) src_ = (const char*)e;                \
            gload_lds16(src_, (char*)&Af[P_][0][0] + rd_ * 8192 + w * 1024 + l * 16); \
        }                                                                       \
    } while (0)

    // B chunk stage: 5 rounds x 8KB, fully linear
#define STAGE_B(KC_, P_) do {                                                   \
        const char* bs_ = (const char*)Bp + (size_t)(KC_) * BCHUNK;             \
        char* bd_ = (char*)&Bf[P_][0];                                          \
        _Pragma("unroll")                                                       \
        for (int rd_ = 0; rd_ < 5; ++rd_)                                       \
            gload_lds16(bs_ + rd_ * 8192 + tid * 16, bd_ + rd_ * 8192 + tid * 16); \
    } while (0)

    float4v acc[GF];
#pragma unroll
    for (int f = 0; f < GF; ++f) acc[f] = (float4v){0.f, 0.f, 0.f, 0.f};

    // compute one chunk (2 sub-ks x 20 frags = 40 MFMA per wave)
#define COMPUTE(P_) do {                                                        \
        const char* ab_ = (const char*)&Af[P_][0][0] + (w * 16 + r) * 256;      \
        const ushort* bb_ = &Bf[P_][0];                                         \
        _Pragma("unroll")                                                       \
        for (int s_ = 0; s_ < 2; ++s_) {                                        \
            int u0_ = (s_ * 8 + 2 * q) ^ r;                                     \
            int u1_ = (s_ * 8 + 2 * q + 1) ^ r;                                 \
            float4v fa0_ = *reinterpret_cast<const float4v*>(ab_ + u0_ * 16);   \
            float4v fa1_ = *reinterpret_cast<const float4v*>(ab_ + u1_ * 16);   \
            short8 fa_ = pack8_cvt(fa0_, fa1_);                                 \
            const ushort* bs_ = bb_ + s_ * (GF * 512) + l * 8;                  \
            _Pragma("unroll")                                                   \
            for (int f_ = 0; f_ < GF; ++f_) {                                   \
                short8 bfr_ = *reinterpret_cast<const short8*>(bs_ + f_ * 512); \
                acc[f_] = __builtin_amdgcn_mfma_f32_16x16x32_bf16(bfr_, fa_, acc[f_], 0, 0, 0); \
            }                                                                   \
        }                                                                       \
    } while (0)

    // ---- pipeline: 9 gloads/thread per chunk; counted vmcnt, never 0 mid-loop ----
    STAGE_A(0, 0); STAGE_B(0, 0);
    STAGE_A(1, 1); STAGE_B(1, 1);
    WAITV(9); BAR();

    COMPUTE(0); BAR();
    STAGE_A(2, 0); STAGE_B(2, 0); WAITV(9); BAR();

    COMPUTE(1); BAR();
    STAGE_A(3, 1); STAGE_B(3, 1); WAITV(9); BAR();

    COMPUTE(0); BAR();
    STAGE_A(4, 0); STAGE_B(4, 0); WAITV(9); BAR();

    COMPUTE(1); BAR();
    WAITV(0); BAR();

    COMPUTE(0);

    // ---- epilogue: out[m][g] = acc + Vx'[i][g] + Vx'[j][g] (Ub folded in Vx') ----
    {
        const int mrow = m0 + w * 16 + r;
        int j = mrow % NN;
        int ti = mrow / NN;       // b*NN + i
        int b = ti / NN;
        const float* vi = Vx + (size_t)ti * HH;
        const float* vj = Vx + (size_t)(b * NN + j) * HH;
        float* orow = out + (size_t)mrow * HH;
#pragma unroll
        for (int f = 0; f < GF - 1; ++f) {     // f=19 entirely >=300
            int g0 = f * 16 + q * 4;
            if (g0 + 4 <= HH) {
                float4v vi4 = *reinterpret_cast<const float4v*>(vi + g0);
                float4v vj4 = *reinterpret_cast<const float4v*>(vj + g0);
                *reinterpret_cast<float4v*>(orow + g0) = acc[f] + vi4 + vj4;
            }
        }
    }
#undef COMPUTE
#undef STAGE_A
#undef STAGE_B
#undef BAR
#undef WAITV
}

extern "C" void kernel_launch(void* const* d_in, const int* in_sizes, int n_in,
                              void* d_out, int out_size, void* d_ws, size_t ws_size,
                              hipStream_t stream) {
    const float* x  = (const float*)d_in[0];
    const float* e  = (const float*)d_in[1];
    const float* Uw = (const float*)d_in[2];
    const float* Ub = (const float*)d_in[3];
    const float* Vw = (const float*)d_in[4];
    const float* Vb = (const float*)d_in[5];
    float* out = (float*)d_out;

    ushort* Bp = (ushort*)d_ws;                              // 204,800 B (frag-packed bf16 U_w)
    float*  Vx = (float*)((char*)d_ws + 204800);             // 960,000 B

    pack_u<<<50, 256, 0, stream>>>(Uw, Bp);
    vx_kernel<<<BB * NN, 256, 0, stream>>>(x, Vw, Vb, Ub, Vx);
    gemm_kernel<<<160000 / BM, 512, 0, stream>>>(e, Bp, Vx, out);
}